// Round 1
// 160.722 us; speedup vs baseline: 1.0116x; 1.0116x over previous
//
#include <hip/hip_runtime.h>
#include <hip/hip_bf16.h>

// Problem constants: p1,p2 : (B=2, C=32, D=H=W=64) fp32. Pool 4x4x4 -> S=16.
// N = B*S^3 = 8192 rows of C=32. loss = ||A Aᵀ - B Bᵀ||_F² / N²
//           = (||AᵀA||² - 2||AᵀB||² + ||BᵀB||²) / N²  with 32x32 Grams only.

#define HW    4096      // 64*64
#define DHW   262144    // 64*64*64
#define NROW  8192
#define C     32
#define NPART 8         // partial Gram copies (atomic-contention spreading)

// ---------------------------------------------------------------------------
// Kernel 1: fused 4x4x4 avg-pool + row L2-normalize — MLP-optimized.
// grid.x = 512 : (b,zo,yo) triples; grid.y = 2 : which input (p1 or p2).
// 1024 threads = 16 waves. Wave wv handles channels {2wv, 2wv+1}.
// Lane = dy*16 + x4 : each wave's load for a given (c,dz) is one fully
// contiguous, 1KiB-aligned line (4 consecutive y-rows x 64 x-floats).
// Each thread issues all 8 float4 loads up-front (register array) so the
// compiler emits 8 back-to-back global_load_dwordx4 -> deep MLP.
// Reduction over dy via 2x shfl_xor; channel-norm via small LDS tile.
// ---------------------------------------------------------------------------
__global__ __launch_bounds__(1024) void pool_norm_kernel(
    const float* __restrict__ p1, const float* __restrict__ p2,
    float* __restrict__ An, float* __restrict__ Bn)
{
    const int bid = blockIdx.x;
    const int yo = bid & 15;
    const int zo = (bid >> 4) & 15;
    const int b  = bid >> 8;

    const float* __restrict__ src = (blockIdx.y == 0) ? p1 : p2;
    float* __restrict__ dst       = (blockIdx.y == 0) ? An : Bn;

    const int tid  = threadIdx.x;
    const int wv   = tid >> 6;       // 0..15
    const int lane = tid & 63;
    const int dy   = lane >> 4;      // 0..3
    const int x4   = lane & 15;      // 0..15 (float4 index along W)

    __shared__ float pool[C][16];    // [channel][x]
    __shared__ float inv_norm[16];

    // ---- issue ALL loads first: 8 independent contiguous-1KiB wave loads
    float4 v[2][4];
    #pragma unroll
    for (int cc = 0; cc < 2; ++cc) {
        const int c = wv * 2 + cc;
        const float* base = src + (size_t)(b * C + c) * DHW
                          + (4 * zo) * HW + (4 * yo + dy) * 64 + 4 * x4;
        #pragma unroll
        for (int dz = 0; dz < 4; ++dz)
            v[cc][dz] = *reinterpret_cast<const float4*>(base + dz * HW);
    }

    // ---- reduce: within-thread (16 vals), then across dy (lanes ^16, ^32)
    #pragma unroll
    for (int cc = 0; cc < 2; ++cc) {
        float s = 0.f;
        #pragma unroll
        for (int dz = 0; dz < 4; ++dz)
            s += (v[cc][dz].x + v[cc][dz].y) + (v[cc][dz].z + v[cc][dz].w);
        s += __shfl_xor(s, 16);
        s += __shfl_xor(s, 32);
        if (lane < 16) pool[wv * 2 + cc][lane] = s * (1.0f / 64.0f);
    }
    __syncthreads();

    if (tid < 16) {
        float ss = 0.f;
        #pragma unroll
        for (int c = 0; c < C; ++c) { const float p = pool[c][tid]; ss += p * p; }
        inv_norm[tid] = 1.0f / fmaxf(sqrtf(ss), 1e-8f);
    }
    __syncthreads();

    // ---- write 16 rows x 32 channels, contiguous in c (coalesced 128B runs)
    if (tid < 512) {
        const int x = tid >> 5;      // 0..15
        const int c = tid & 31;      // 0..31
        const int row = ((b * 16 + zo) * 16 + yo) * 16 + x;
        dst[(size_t)row * C + c] = pool[c][x] * inv_norm[x];
    }
}

// ---------------------------------------------------------------------------
// Kernel 2: three 32x32 Grams: Gaa = AᵀA, Gab = AᵀB, Gbb = BᵀB.
// 256 blocks x 256 threads, 32 rows/block (full CU coverage, single tile).
// Thread t owns entries (k = t>>3, l = (t&7)*4 .. +3) of all three Grams
// (12 accumulators), atomicAdds into one of NPART partial G copies.
// ---------------------------------------------------------------------------
__global__ __launch_bounds__(256) void gram_kernel(
    const float* __restrict__ An, const float* __restrict__ Bn,
    float* __restrict__ G)   // NPART copies of [0..1023]=Gaa [1024..2047]=Gab [2048..3071]=Gbb
{
    const int tid = threadIdx.x;
    const int k  = tid >> 3;          // 0..31
    const int l4 = (tid & 7) * 4;     // 0,4,...,28

    __shared__ float As[32 * C];
    __shared__ float Bs[32 * C];

    float gaa[4] = {0.f, 0.f, 0.f, 0.f};
    float gab[4] = {0.f, 0.f, 0.f, 0.f};
    float gbb[4] = {0.f, 0.f, 0.f, 0.f};

    const int r = blockIdx.x * 32;
    reinterpret_cast<float4*>(As)[tid] =
        reinterpret_cast<const float4*>(An + (size_t)r * C)[tid];
    reinterpret_cast<float4*>(Bs)[tid] =
        reinterpret_cast<const float4*>(Bn + (size_t)r * C)[tid];
    __syncthreads();

    #pragma unroll
    for (int i = 0; i < 32; ++i) {
        const float a_k = As[i * C + k];
        const float b_k = Bs[i * C + k];
        const float4 a_l = *reinterpret_cast<const float4*>(&As[i * C + l4]);
        const float4 b_l = *reinterpret_cast<const float4*>(&Bs[i * C + l4]);
        gaa[0] += a_k * a_l.x;  gaa[1] += a_k * a_l.y;
        gaa[2] += a_k * a_l.z;  gaa[3] += a_k * a_l.w;
        gab[0] += a_k * b_l.x;  gab[1] += a_k * b_l.y;
        gab[2] += a_k * b_l.z;  gab[3] += a_k * b_l.w;
        gbb[0] += b_k * b_l.x;  gbb[1] += b_k * b_l.y;
        gbb[2] += b_k * b_l.z;  gbb[3] += b_k * b_l.w;
    }

    float* Gp = G + (size_t)(blockIdx.x & (NPART - 1)) * 3072;
    #pragma unroll
    for (int j = 0; j < 4; ++j) {
        atomicAdd(&Gp[k * C + l4 + j],        gaa[j]);
        atomicAdd(&Gp[1024 + k * C + l4 + j], gab[j]);
        atomicAdd(&Gp[2048 + k * C + l4 + j], gbb[j]);
    }
}

// ---------------------------------------------------------------------------
// Kernel 3: loss = (sum Gaa² - 2 sum Gab² + sum Gbb²) / N²  (sums NPART parts)
// ---------------------------------------------------------------------------
__global__ __launch_bounds__(1024) void finalize_kernel(
    const float* __restrict__ G, float* __restrict__ out)
{
    const int t = threadIdx.x;
    float gaa = 0.f, gab = 0.f, gbb = 0.f;
    #pragma unroll
    for (int p = 0; p < NPART; ++p) {
        gaa += G[p * 3072 + t];
        gab += G[p * 3072 + 1024 + t];
        gbb += G[p * 3072 + 2048 + t];
    }
    float v = gaa * gaa + gbb * gbb - 2.f * gab * gab;

    __shared__ float red[16];
    #pragma unroll
    for (int off = 32; off > 0; off >>= 1) v += __shfl_down(v, off);
    if ((t & 63) == 0) red[t >> 6] = v;
    __syncthreads();
    if (t < 16) {
        float w = red[t];
        #pragma unroll
        for (int off = 8; off > 0; off >>= 1) w += __shfl_down(w, off);
        if (t == 0) out[0] = w / ((float)NROW * (float)NROW);
    }
}

extern "C" void kernel_launch(void* const* d_in, const int* in_sizes, int n_in,
                              void* d_out, int out_size, void* d_ws, size_t ws_size,
                              hipStream_t stream) {
    const float* p1 = (const float*)d_in[0];
    const float* p2 = (const float*)d_in[1];
    float* out = (float*)d_out;

    float* An = (float*)d_ws;                    // 8192*32 floats = 1 MiB
    float* Bn = An + (size_t)NROW * C;           // 1 MiB
    float* G  = Bn + (size_t)NROW * C;           // NPART*3072 floats = 96 KiB

    hipMemsetAsync(G, 0, NPART * 3072 * sizeof(float), stream);

    dim3 g1(512, 2);
    pool_norm_kernel<<<g1, 1024, 0, stream>>>(p1, p2, An, Bn);
    gram_kernel<<<256, 256, 0, stream>>>(An, Bn, G);
    finalize_kernel<<<1, 1024, 0, stream>>>(G, out);
}

// Round 2
// 151.339 us; speedup vs baseline: 1.0743x; 1.0620x over previous
//
#include <hip/hip_runtime.h>
#include <hip/hip_bf16.h>

// Problem: p1,p2 : (B=2, C=32, D=H=W=64) fp32. Pool 4x4x4 -> S=16.
// N = B*S^3 = 8192 rows of C=32. loss = ||A Aᵀ - B Bᵀ||_F² / N²
//           = (||AᵀA||² - 2||AᵀB||² + ||BᵀB||²) / N²  with 32x32 Grams only.
//
// v3: single fused kernel. Each block (b,zo,yo) loads BOTH inputs' 4x4x4
// neighborhoods for its 16 output rows, pools, normalizes, and accumulates
// the three 32x32 Gram partials directly (atomicAdd into NPART spread
// copies). Eliminates the gram kernel, its launch gap, and the An/Bn
// intermediate entirely. sched_barrier(0) after the load cluster forces
// all 16 float4 loads in flight per thread (round-1 showed the compiler
// collapsed them to ~2 in flight: VGPR_Count=20).

#define HW    4096      // 64*64
#define DHW   262144    // 64*64*64
#define NROW  8192
#define C     32
#define NPART 16        // partial Gram copies (atomic-contention spreading)

// ---------------------------------------------------------------------------
// Fused pool + normalize + Gram partials.
// grid = 512 : (b,zo,yo). 1024 threads = 16 waves.
// Wave wv handles channels {2wv, 2wv+1} of BOTH inputs.
// Lane = dy*16 + x4 : each wave-load is one contiguous 1KiB line.
// ---------------------------------------------------------------------------
__global__ __launch_bounds__(1024) void fused_pool_gram_kernel(
    const float* __restrict__ p1, const float* __restrict__ p2,
    float* __restrict__ G)
{
    const int bid = blockIdx.x;
    const int yo = bid & 15;
    const int zo = (bid >> 4) & 15;
    const int b  = bid >> 8;

    const int tid  = threadIdx.x;
    const int wv   = tid >> 6;       // 0..15
    const int lane = tid & 63;
    const int dy   = lane >> 4;      // 0..3
    const int x4   = lane & 15;      // 0..15 (float4 index along W)

    __shared__ float pa[C][17];      // +1 pad: stride-17 kills bank conflicts
    __shared__ float pb[C][17];
    __shared__ float inva[16];
    __shared__ float invb[16];

    const size_t sp_off = (size_t)(4 * zo) * HW + (size_t)(4 * yo + dy) * 64 + 4 * x4;

    // ---- issue ALL 16 loads first; sched_barrier(0) pins them above the math
    float4 va[2][4], vb[2][4];
    #pragma unroll
    for (int cc = 0; cc < 2; ++cc) {
        const int c = wv * 2 + cc;
        const float* basea = p1 + (size_t)(b * C + c) * DHW + sp_off;
        const float* baseb = p2 + (size_t)(b * C + c) * DHW + sp_off;
        #pragma unroll
        for (int dz = 0; dz < 4; ++dz) {
            va[cc][dz] = *reinterpret_cast<const float4*>(basea + dz * HW);
            vb[cc][dz] = *reinterpret_cast<const float4*>(baseb + dz * HW);
        }
    }
    __builtin_amdgcn_sched_barrier(0);

    // ---- reduce: within-thread, then across dy (lanes ^16, ^32)
    #pragma unroll
    for (int cc = 0; cc < 2; ++cc) {
        float sa = 0.f, sb = 0.f;
        #pragma unroll
        for (int dz = 0; dz < 4; ++dz) {
            sa += (va[cc][dz].x + va[cc][dz].y) + (va[cc][dz].z + va[cc][dz].w);
            sb += (vb[cc][dz].x + vb[cc][dz].y) + (vb[cc][dz].z + vb[cc][dz].w);
        }
        sa += __shfl_xor(sa, 16);  sa += __shfl_xor(sa, 32);
        sb += __shfl_xor(sb, 16);  sb += __shfl_xor(sb, 32);
        if (lane < 16) {
            pa[wv * 2 + cc][lane] = sa * (1.0f / 64.0f);
            pb[wv * 2 + cc][lane] = sb * (1.0f / 64.0f);
        }
    }
    __syncthreads();

    // ---- per-row inverse norms (rows are the 16 x-positions)
    if (tid < 32) {
        const int x = tid & 15;
        float ss = 0.f;
        if (tid < 16) {
            #pragma unroll
            for (int c2 = 0; c2 < C; ++c2) { const float v = pa[c2][x]; ss += v * v; }
            inva[x] = 1.0f / fmaxf(sqrtf(ss), 1e-8f);
        } else {
            #pragma unroll
            for (int c2 = 0; c2 < C; ++c2) { const float v = pb[c2][x]; ss += v * v; }
            invb[x] = 1.0f / fmaxf(sqrtf(ss), 1e-8f);
        }
    }
    __syncthreads();

    // ---- normalize in place (1024 threads cover 2 x 32 x 16 entries)
    {
        const int sel = tid >> 9;        // 0: pa, 1: pb
        const int c   = (tid >> 4) & 31;
        const int x   = tid & 15;
        if (sel == 0) pa[c][x] *= inva[x];
        else          pb[c][x] *= invb[x];
    }
    __syncthreads();

    // ---- Gram partials over this block's 16 rows: thread t owns (k,l)
    const int k = tid >> 5;              // 0..31
    const int l = tid & 31;              // 0..31
    float gaa = 0.f, gab = 0.f, gbb = 0.f;
    #pragma unroll
    for (int x = 0; x < 16; ++x) {
        const float ak = pa[k][x];       // broadcast within half-wave
        const float al = pa[l][x];       // stride-17: conflict-free
        const float bk = pb[k][x];
        const float bl = pb[l][x];
        gaa += ak * al;
        gab += ak * bl;
        gbb += bk * bl;
    }

    float* Gp = G + (size_t)(bid & (NPART - 1)) * 3072;
    atomicAdd(&Gp[       k * 32 + l], gaa);
    atomicAdd(&Gp[1024 + k * 32 + l], gab);
    atomicAdd(&Gp[2048 + k * 32 + l], gbb);
}

// ---------------------------------------------------------------------------
// Finalize: loss = (sum Gaa² - 2 sum Gab² + sum Gbb²) / N²  (sum NPART parts
// per entry BEFORE squaring).
// ---------------------------------------------------------------------------
__global__ __launch_bounds__(1024) void finalize_kernel(
    const float* __restrict__ G, float* __restrict__ out)
{
    const int t = threadIdx.x;
    float gaa = 0.f, gab = 0.f, gbb = 0.f;
    #pragma unroll
    for (int p = 0; p < NPART; ++p) {
        gaa += G[p * 3072 + t];
        gab += G[p * 3072 + 1024 + t];
        gbb += G[p * 3072 + 2048 + t];
    }
    float v = gaa * gaa + gbb * gbb - 2.f * gab * gab;

    __shared__ float red[16];
    #pragma unroll
    for (int off = 32; off > 0; off >>= 1) v += __shfl_down(v, off);
    if ((t & 63) == 0) red[t >> 6] = v;
    __syncthreads();
    if (t < 16) {
        float w = red[t];
        #pragma unroll
        for (int off = 8; off > 0; off >>= 1) w += __shfl_down(w, off);
        if (t == 0) out[0] = w / ((float)NROW * (float)NROW);
    }
}

extern "C" void kernel_launch(void* const* d_in, const int* in_sizes, int n_in,
                              void* d_out, int out_size, void* d_ws, size_t ws_size,
                              hipStream_t stream) {
    const float* p1 = (const float*)d_in[0];
    const float* p2 = (const float*)d_in[1];
    float* out = (float*)d_out;

    float* G = (float*)d_ws;   // NPART * 3072 floats = 192 KiB

    hipMemsetAsync(G, 0, NPART * 3072 * sizeof(float), stream);

    fused_pool_gram_kernel<<<512, 1024, 0, stream>>>(p1, p2, G);
    finalize_kernel<<<1, 1024, 0, stream>>>(G, out);
}